// Round 4
// baseline (232.705 us; speedup 1.0000x reference)
//
#include <hip/hip_runtime.h>

#define NB   32
#define NT   784
#define NC   768
#define NH   4
#define CH   192
#define PSZ  14
#define NP   196
#define RESO 28
#define EPSV 1e-5f
#define JXB  2            // jx columns per block
#define NJT  (PSZ / JXB)  // 7 jx-tiles

// ---------------------------------------------------------------------------
// K1: wave-per-token group-m2 norm + per-token mean/var + 2x2 pool.
// grid = NB*NP blocks of 256 (4 waves = 4 tokens of one patch).
// Head-aligned lanes: lane L owns head L/16, channels (L%16)*12..+11
// -> m2 reduce is 4 shfl rounds within a 16-lane group (no masking).
// ---------------------------------------------------------------------------
__global__ __launch_bounds__(256) void k_norm_pool(
    const float* __restrict__ x,
    float* __restrict__ inv_m2, float* __restrict__ mean_ln,
    float* __restrict__ var_ln, float4* __restrict__ xp4) {
  __shared__ float4 xl4[4 * 192];  // 12.3 KB
  int bid = blockIdx.x;
  int b = bid / NP, ip = bid % NP;
  int pr = ip / PSZ, pc = ip % PSZ;
  int tid = threadIdx.x;
  int k = tid >> 6, lane = tid & 63;
  int t = (2 * pr + (k >> 1)) * RESO + (2 * pc + (k & 1));

  const float4* row = (const float4*)(x + (size_t)(b * NT + t) * NC);
  int f4b = (lane >> 4) * 48 + (lane & 15) * 3;  // lane's base float4 index
  float4 v0 = row[f4b], v1 = row[f4b + 1], v2 = row[f4b + 2];

  // group-m2: all 12 channels of this lane belong to one head
  float d = v0.x * v0.x + v0.y * v0.y + v0.z * v0.z + v0.w * v0.w +
            v1.x * v1.x + v1.y * v1.y + v1.z * v1.z + v1.w * v1.w +
            v2.x * v2.x + v2.y * v2.y + v2.z * v2.z + v2.w * v2.w;
#pragma unroll
  for (int s = 1; s <= 8; s <<= 1) d += __shfl_xor(d, s, 64);
  float iv = rsqrtf(d * (1.f / CH) + EPSV);
  if ((lane & 15) == 0)
    inv_m2[(size_t)(b * NT + t) * NH + (lane >> 4)] = iv;

  v0.x *= iv; v0.y *= iv; v0.z *= iv; v0.w *= iv;
  v1.x *= iv; v1.y *= iv; v1.z *= iv; v1.w *= iv;
  v2.x *= iv; v2.y *= iv; v2.z *= iv; v2.w *= iv;

  float sm = v0.x + v0.y + v0.z + v0.w + v1.x + v1.y + v1.z + v1.w +
             v2.x + v2.y + v2.z + v2.w;
  float sq = v0.x * v0.x + v0.y * v0.y + v0.z * v0.z + v0.w * v0.w +
             v1.x * v1.x + v1.y * v1.y + v1.z * v1.z + v1.w * v1.w +
             v2.x * v2.x + v2.y * v2.y + v2.z * v2.z + v2.w * v2.w;
#pragma unroll
  for (int s = 1; s <= 32; s <<= 1) {
    sm += __shfl_xor(sm, s, 64);
    sq += __shfl_xor(sq, s, 64);
  }
  if (lane == 0) {
    float mean = sm / (float)NC;
    mean_ln[b * NT + t] = mean;
    var_ln[b * NT + t] = (sq - (float)NC * mean * mean) / (float)(NC - 1);
  }

  xl4[k * 192 + f4b]     = v0;
  xl4[k * 192 + f4b + 1] = v1;
  xl4[k * 192 + f4b + 2] = v2;
  __syncthreads();

  if (tid < 192) {
    float4 a = xl4[tid], bb = xl4[192 + tid], c = xl4[384 + tid], dd = xl4[576 + tid];
    float4 r;
    r.x = (a.x + bb.x + c.x + dd.x) * 0.25f;
    r.y = (a.y + bb.y + c.y + dd.y) * 0.25f;
    r.z = (a.z + bb.z + c.z + dd.z) * 0.25f;
    r.w = (a.w + bb.w + c.w + dd.w) * 0.25f;
    xp4[(size_t)(b * NP + ip) * 192 + tid] = r;
  }
}

// ---------------------------------------------------------------------------
// K2: separable conv + blend + affine + store, JXB=2 jx-columns per block.
// grid = NB*3*NJT = 672 blocks of 256 (XCD-swizzled, 672 = 8*84).
// Thread owns ONE channel c = h*192 + s*64 + lane; each xp element fuels
// 4 FMAs (t1/t2 for both jx columns) -> xp L2 re-read halves vs JXB=1.
// ---------------------------------------------------------------------------
__global__ __launch_bounds__(256) void k_fused(
    const float* __restrict__ xp, const float* __restrict__ pos_w,
    const float* __restrict__ mnw, const float* __restrict__ vnw,
    const float* __restrict__ x,
    const float* __restrict__ weight, const float* __restrict__ bias,
    const float* __restrict__ inv_m2, const float* __restrict__ mean_ln,
    const float* __restrict__ var_ln, float* __restrict__ out) {
  __shared__ float fns[JXB][NH * PSZ];     // F rows for jx0, jx0+1, per head
  __shared__ float gns[NH * PSZ * PSZ];    // full G tables
  __shared__ float tstat[JXB][4 * PSZ][6]; // per local token: inv_m2[4], mean, var
  __shared__ float sgate[8];               // sigmoid(mnw), sigmoid(vnw)

  int bid0 = blockIdx.x;
  int bid = (bid0 & 7) * 84 + (bid0 >> 3);  // bijective XCD swizzle (672 = 8*84)
  int b = bid / (3 * NJT), r = bid % (3 * NJT);
  int s = r / NJT, jt = r % NJT;
  int jx0 = jt * JXB;
  int tid = threadIdx.x;
  int h = tid >> 6, lane = tid & 63;
  int c = h * CH + s * 64 + lane;

  // ---- in-block separable softmax tables (disjoint thread ranges)
  if (tid < NH * PSZ) {                  // tid 0..55: G row, head tid/14, jy=tid%14
    int hh = tid / PSZ, jr = tid % PSZ;
    float w1 = pos_w[hh * 3 + 1], w2 = pos_w[hh * 3 + 2];
    float e[PSZ], mx = -1e30f;
#pragma unroll
    for (int i = 0; i < PSZ; ++i) {
      float dd = (float)(jr - i);
      float sc = w1 * dd + w2 * dd * dd;
      e[i] = sc; mx = fmaxf(mx, sc);
    }
    float sum = 0.f;
#pragma unroll
    for (int i = 0; i < PSZ; ++i) { e[i] = expf(e[i] - mx); sum += e[i]; }
    float invs = 1.f / sum;
#pragma unroll
    for (int i = 0; i < PSZ; ++i) gns[(hh * PSZ + jr) * PSZ + i] = e[i] * invs;
  }
  if (tid >= 64 && tid < 64 + JXB * NH) { // tid 64..71: F rows, jj = (tid-64)>>2, head &3
    int idx = tid - 64;
    int jj = idx >> 2, hh = idx & 3;
    int jxx = jx0 + jj;
    float w0 = pos_w[hh * 3 + 0], w2 = pos_w[hh * 3 + 2];
    float e[PSZ], mx = -1e30f;
#pragma unroll
    for (int i = 0; i < PSZ; ++i) {
      float dd = (float)(jxx - i);
      float sc = w0 * dd + w2 * dd * dd;
      e[i] = sc; mx = fmaxf(mx, sc);
    }
    float sum = 0.f;
#pragma unroll
    for (int i = 0; i < PSZ; ++i) { e[i] = expf(e[i] - mx); sum += e[i]; }
    float invs = 1.f / sum;
#pragma unroll
    for (int i = 0; i < PSZ; ++i) fns[jj][hh * PSZ + i] = e[i] * invs;
  }
  if (tid >= 72 && tid < 80) {           // tid 72..79: sigmoid gates
    int g = tid - 72;
    float v = (g < 4) ? mnw[g] : vnw[g - 4];
    sgate[g] = 1.f / (1.f + expf(-v));
  }
  for (int idx = tid; idx < JXB * 4 * PSZ * 6; idx += 256) {
    int jj = idx / (4 * PSZ * 6), rem = idx % (4 * PSZ * 6);
    int l = rem / 6, f = rem % 6;
    int jy = l >> 2, kk = l & 3;
    int jxx = jx0 + jj;
    int t = (2 * jy + (kk >> 1)) * RESO + (2 * jxx + (kk & 1));
    size_t o = (size_t)(b * NT + t);
    tstat[jj][l][f] = (f < 4) ? inv_m2[o * NH + f]
                    : (f == 4) ? mean_ln[o] : var_ln[o];
  }
  __syncthreads();

  // ---- Pass A: x-direction 14-tap contraction for both jx columns.
  // Outer ix so F-values load once per ix (2 ds_reads), inner iy unrolled.
  float t1[JXB][PSZ], t2[JXB][PSZ];
#pragma unroll
  for (int jj = 0; jj < JXB; ++jj)
#pragma unroll
    for (int iy = 0; iy < PSZ; ++iy) { t1[jj][iy] = 0.f; t2[jj][iy] = 0.f; }

  const float* base = xp + (size_t)b * NP * NC + c;
#pragma unroll
  for (int ix = 0; ix < PSZ; ++ix) {
    float fA = fns[0][h * PSZ + ix];  // wave-uniform LDS broadcast
    float fB = fns[1][h * PSZ + ix];
#pragma unroll
    for (int iy = 0; iy < PSZ; ++iy) {
      float v = base[(size_t)(iy * PSZ + ix) * NC];
      float vv = v * v;
      t1[0][iy] += fA * v;  t2[0][iy] += fA * vv;
      t1[1][iy] += fB * v;  t2[1][iy] += fB * vv;
    }
  }

  // ---- Pass B + epilogue (jj fully unrolled -> all t1/t2 indices static)
  float wv = weight[c], bv = bias[c];
  float mw = sgate[h], vw = sgate[4 + h];
  float omw = 1.f - mw, ovw = 1.f - vw;
  const float* gh = &gns[h * NP];

#pragma unroll
  for (int jj = 0; jj < JXB; ++jj) {
    int jxx = jx0 + jj;
#pragma unroll 1
    for (int jy = 0; jy < PSZ; ++jy) {
      float m = 0.f, q = 0.f;
#pragma unroll
      for (int iy = 0; iy < PSZ; ++iy) {
        float g = gh[jy * PSZ + iy];  // wave-uniform LDS broadcast
        m += g * t1[jj][iy];
        q += g * t2[jj][iy];
      }
      float p = fmaxf(q - m * m, 0.f);
      float mb = omw * m, vb = ovw * p;

#pragma unroll
      for (int kk = 0; kk < 4; ++kk) {
        int t = (2 * jy + (kk >> 1)) * RESO + (2 * jxx + (kk & 1));
        size_t xo = (size_t)(b * NT + t) * NC;
        int l = jy * 4 + kk;
        float ivv = tstat[jj][l][h];
        float ml = tstat[jj][l][4], vl = tstat[jj][l][5];

        float xn = x[xo + c] * ivv;
        float mr = mb + mw * ml;
        float vr = vb + vw * vl;
        out[xo + c] = (xn - mr) * rsqrtf(vr + EPSV) * wv + bv;
      }
    }
  }
}

// ---------------------------------------------------------------------------
extern "C" void kernel_launch(void* const* d_in, const int* in_sizes, int n_in,
                              void* d_out, int out_size, void* d_ws, size_t ws_size,
                              hipStream_t stream) {
  const float* x     = (const float*)d_in[0];
  const float* wgt   = (const float*)d_in[1];
  const float* bias  = (const float*)d_in[2];
  const float* mnw   = (const float*)d_in[3];
  const float* vnw   = (const float*)d_in[4];
  const float* pos_w = (const float*)d_in[5];
  // pos_b (d_in[6]) cancels in the softmax — unused.
  float* out = (float*)d_out;

  float* ws      = (float*)d_ws;
  float* inv_m2  = ws;                              // NB*NT*NH = 100352
  float* mean_ln = inv_m2 + (size_t)NB * NT * NH;   // 25088
  float* var_ln  = mean_ln + (size_t)NB * NT;       // 25088
  float* xp      = var_ln + (size_t)NB * NT;        // NB*NP*NC = 4816896 (16B aligned)
  // total ~19.9 MB of workspace

  hipLaunchKernelGGL(k_norm_pool, dim3(NB * NP), dim3(256), 0, stream,
                     x, inv_m2, mean_ln, var_ln, (float4*)xp);
  hipLaunchKernelGGL(k_fused, dim3(NB * 3 * NJT), dim3(256), 0, stream,
                     xp, pos_w, mnw, vnw, x, wgt, bias, inv_m2, mean_ln, var_ln, out);
}

// Round 5
// 213.675 us; speedup vs baseline: 1.0891x; 1.0891x over previous
//
#include <hip/hip_runtime.h>

#define NB   32
#define NT   784
#define NC   768
#define NH   4
#define CH   192
#define PSZ  14
#define NP   196
#define RESO 28
#define EPSV 1e-5f
#define NSL  192   // float4 channel-slots per token (768/4)

// ---------------------------------------------------------------------------
// K1: wave-per-token group-m2 norm + per-token mean/var + 2x2 pool.
// grid = NB*NP blocks of 256 (4 waves = 4 tokens of one patch).
// Head-aligned lanes: lane L owns head L/16, channels (L%16)*12..+11
// -> m2 reduce is 4 shfl rounds within a 16-lane group (no masking).
// ---------------------------------------------------------------------------
__global__ __launch_bounds__(256) void k_norm_pool(
    const float* __restrict__ x,
    float* __restrict__ inv_m2, float* __restrict__ mean_ln,
    float* __restrict__ var_ln, float4* __restrict__ xp4) {
  __shared__ float4 xl4[4 * 192];  // 12.3 KB
  int bid = blockIdx.x;
  int b = bid / NP, ip = bid % NP;
  int pr = ip / PSZ, pc = ip % PSZ;
  int tid = threadIdx.x;
  int k = tid >> 6, lane = tid & 63;
  int t = (2 * pr + (k >> 1)) * RESO + (2 * pc + (k & 1));

  const float4* row = (const float4*)(x + (size_t)(b * NT + t) * NC);
  int f4b = (lane >> 4) * 48 + (lane & 15) * 3;  // lane's base float4 index
  float4 v0 = row[f4b], v1 = row[f4b + 1], v2 = row[f4b + 2];

  // group-m2: all 12 channels of this lane belong to one head
  float d = v0.x * v0.x + v0.y * v0.y + v0.z * v0.z + v0.w * v0.w +
            v1.x * v1.x + v1.y * v1.y + v1.z * v1.z + v1.w * v1.w +
            v2.x * v2.x + v2.y * v2.y + v2.z * v2.z + v2.w * v2.w;
#pragma unroll
  for (int s = 1; s <= 8; s <<= 1) d += __shfl_xor(d, s, 64);
  float iv = rsqrtf(d * (1.f / CH) + EPSV);
  if ((lane & 15) == 0)
    inv_m2[(size_t)(b * NT + t) * NH + (lane >> 4)] = iv;

  v0.x *= iv; v0.y *= iv; v0.z *= iv; v0.w *= iv;
  v1.x *= iv; v1.y *= iv; v1.z *= iv; v1.w *= iv;
  v2.x *= iv; v2.y *= iv; v2.z *= iv; v2.w *= iv;

  float sm = v0.x + v0.y + v0.z + v0.w + v1.x + v1.y + v1.z + v1.w +
             v2.x + v2.y + v2.z + v2.w;
  float sq = v0.x * v0.x + v0.y * v0.y + v0.z * v0.z + v0.w * v0.w +
             v1.x * v1.x + v1.y * v1.y + v1.z * v1.z + v1.w * v1.w +
             v2.x * v2.x + v2.y * v2.y + v2.z * v2.z + v2.w * v2.w;
#pragma unroll
  for (int s = 1; s <= 32; s <<= 1) {
    sm += __shfl_xor(sm, s, 64);
    sq += __shfl_xor(sq, s, 64);
  }
  if (lane == 0) {
    float mean = sm / (float)NC;
    mean_ln[b * NT + t] = mean;
    var_ln[b * NT + t] = (sq - (float)NC * mean * mean) / (float)(NC - 1);
  }

  xl4[k * 192 + f4b]     = v0;
  xl4[k * 192 + f4b + 1] = v1;
  xl4[k * 192 + f4b + 2] = v2;
  __syncthreads();

  if (tid < 192) {
    float4 a = xl4[tid], bb = xl4[192 + tid], c = xl4[384 + tid], dd = xl4[576 + tid];
    float4 r;
    r.x = (a.x + bb.x + c.x + dd.x) * 0.25f;
    r.y = (a.y + bb.y + c.y + dd.y) * 0.25f;
    r.z = (a.z + bb.z + c.z + dd.z) * 0.25f;
    r.w = (a.w + bb.w + c.w + dd.w) * 0.25f;
    xp4[(size_t)(b * NP + ip) * 192 + tid] = r;
  }
}

// ---------------------------------------------------------------------------
// K2: separable conv + blend + affine + store, FLOAT4 per thread.
// grid = NB*PSZ = 448 blocks of 192 (XCD-swizzled, 448 = 8*56).
// Thread tid owns channels 4*tid..4*tid+3 (head = tid/48); all hot global
// accesses are dwordx4 -> 4x fewer vmem instructions than the scalar version
// (the measured bottleneck: vmem issue at ~16 cyc/wave-inst).
// Pass A order iy-outer/ix-inner (R1/R3-proven codegen, bounded VGPR).
// ---------------------------------------------------------------------------
__global__ __launch_bounds__(192) void k_fused(
    const float4* __restrict__ xp4, const float* __restrict__ pos_w,
    const float* __restrict__ mnw, const float* __restrict__ vnw,
    const float4* __restrict__ x4,
    const float4* __restrict__ weight4, const float4* __restrict__ bias4,
    const float* __restrict__ inv_m2, const float* __restrict__ mean_ln,
    const float* __restrict__ var_ln, float4* __restrict__ out4) {
  __shared__ float fns[NH * PSZ];        // F row for this jx, per head
  __shared__ float gns[NH * PSZ * PSZ];  // full G tables
  __shared__ float tstat[4 * PSZ][6];    // per local token: inv_m2[4], mean, var
  __shared__ float sgate[8];             // sigmoid(mnw), sigmoid(vnw)

  int bid0 = blockIdx.x;
  int bid = (bid0 & 7) * 56 + (bid0 >> 3);  // bijective XCD swizzle (448 = 8*56)
  int b = bid / PSZ, jx = bid % PSZ;
  int tid = threadIdx.x;                    // 0..191 = float4 slot
  int h = tid / 48;                         // head of all 4 owned channels

  // ---- in-block separable softmax tables (disjoint thread ranges)
  if (tid < NH * PSZ) {                  // tid 0..55: G row, head tid/14, jy=tid%14
    int hh = tid / PSZ, jr = tid % PSZ;
    float w1 = pos_w[hh * 3 + 1], w2 = pos_w[hh * 3 + 2];
    float e[PSZ], mx = -1e30f;
#pragma unroll
    for (int i = 0; i < PSZ; ++i) {
      float dd = (float)(jr - i);
      float sc = w1 * dd + w2 * dd * dd;
      e[i] = sc; mx = fmaxf(mx, sc);
    }
    float sum = 0.f;
#pragma unroll
    for (int i = 0; i < PSZ; ++i) { e[i] = expf(e[i] - mx); sum += e[i]; }
    float invs = 1.f / sum;
#pragma unroll
    for (int i = 0; i < PSZ; ++i) gns[(hh * PSZ + jr) * PSZ + i] = e[i] * invs;
  }
  if (tid >= 64 && tid < 64 + NH) {      // tid 64..67: F row for this jx, head tid-64
    int hh = tid - 64;
    float w0 = pos_w[hh * 3 + 0], w2 = pos_w[hh * 3 + 2];
    float e[PSZ], mx = -1e30f;
#pragma unroll
    for (int i = 0; i < PSZ; ++i) {
      float dd = (float)(jx - i);
      float sc = w0 * dd + w2 * dd * dd;
      e[i] = sc; mx = fmaxf(mx, sc);
    }
    float sum = 0.f;
#pragma unroll
    for (int i = 0; i < PSZ; ++i) { e[i] = expf(e[i] - mx); sum += e[i]; }
    float invs = 1.f / sum;
#pragma unroll
    for (int i = 0; i < PSZ; ++i) fns[hh * PSZ + i] = e[i] * invs;
  }
  if (tid >= 72 && tid < 80) {           // tid 72..79: sigmoid gates
    int g = tid - 72;
    float v = (g < 4) ? mnw[g] : vnw[g - 4];
    sgate[g] = 1.f / (1.f + expf(-v));
  }
  for (int idx = tid; idx < 4 * PSZ * 6; idx += 192) {
    int l = idx / 6, f = idx % 6;
    int jy = l >> 2, kk = l & 3;
    int t = (2 * jy + (kk >> 1)) * RESO + (2 * jx + (kk & 1));
    size_t o = (size_t)(b * NT + t);
    tstat[l][f] = (f < 4) ? inv_m2[o * NH + f]
                : (f == 4) ? mean_ln[o] : var_ln[o];
  }
  __syncthreads();

  // ---- Pass A: x-direction 14-tap contraction (float4 accumulators)
  float4 t1[PSZ], t2[PSZ];
#pragma unroll
  for (int iy = 0; iy < PSZ; ++iy) {
    t1[iy].x = t1[iy].y = t1[iy].z = t1[iy].w = 0.f;
    t2[iy].x = t2[iy].y = t2[iy].z = t2[iy].w = 0.f;
  }

  const float4* base = xp4 + (size_t)b * NP * NSL + tid;
#pragma unroll
  for (int iy = 0; iy < PSZ; ++iy) {
#pragma unroll
    for (int ix = 0; ix < PSZ; ++ix) {
      float f = fns[h * PSZ + ix];  // LDS broadcast (<=2 addrs per wave)
      float4 v = base[(size_t)(iy * PSZ + ix) * NSL];
      float ax = f * v.x, ay = f * v.y, az = f * v.z, aw = f * v.w;
      t1[iy].x += ax;        t1[iy].y += ay;
      t1[iy].z += az;        t1[iy].w += aw;
      t2[iy].x += ax * v.x;  t2[iy].y += ay * v.y;
      t2[iy].z += az * v.z;  t2[iy].w += aw * v.w;
    }
  }

  // ---- Pass B + epilogue (all float4)
  float4 wv = weight4[tid], bv = bias4[tid];
  float mw = sgate[h], vw = sgate[4 + h];
  float omw = 1.f - mw, ovw = 1.f - vw;
  const float* gh = &gns[h * NP];
  const float4* xb = x4 + (size_t)b * NT * NSL + tid;
  float4* ob = out4 + (size_t)b * NT * NSL + tid;

#pragma unroll 1
  for (int jy = 0; jy < PSZ; ++jy) {
    float4 m, q;
    m.x = m.y = m.z = m.w = 0.f;
    q.x = q.y = q.z = q.w = 0.f;
#pragma unroll
    for (int iy = 0; iy < PSZ; ++iy) {
      float g = gh[jy * PSZ + iy];  // LDS broadcast
      m.x += g * t1[iy].x; m.y += g * t1[iy].y;
      m.z += g * t1[iy].z; m.w += g * t1[iy].w;
      q.x += g * t2[iy].x; q.y += g * t2[iy].y;
      q.z += g * t2[iy].z; q.w += g * t2[iy].w;
    }
    float4 mb, vb;
    mb.x = omw * m.x; mb.y = omw * m.y; mb.z = omw * m.z; mb.w = omw * m.w;
    vb.x = ovw * fmaxf(q.x - m.x * m.x, 0.f);
    vb.y = ovw * fmaxf(q.y - m.y * m.y, 0.f);
    vb.z = ovw * fmaxf(q.z - m.z * m.z, 0.f);
    vb.w = ovw * fmaxf(q.w - m.w * m.w, 0.f);

#pragma unroll
    for (int kk = 0; kk < 4; ++kk) {
      int t = (2 * jy + (kk >> 1)) * RESO + (2 * jx + (kk & 1));
      int l = jy * 4 + kk;
      float ivv = tstat[l][h];
      float ml = tstat[l][4], vl = tstat[l][5];
      float mr = mw * ml;             // token-level parts (per-channel added below)
      float vr = vw * vl + EPSV;

      float4 xv = xb[(size_t)t * NSL];
      float4 r;
      r.x = (xv.x * ivv - (mb.x + mr)) * rsqrtf(vb.x + vr) * wv.x + bv.x;
      r.y = (xv.y * ivv - (mb.y + mr)) * rsqrtf(vb.y + vr) * wv.y + bv.y;
      r.z = (xv.z * ivv - (mb.z + mr)) * rsqrtf(vb.z + vr) * wv.z + bv.z;
      r.w = (xv.w * ivv - (mb.w + mr)) * rsqrtf(vb.w + vr) * wv.w + bv.w;
      ob[(size_t)t * NSL] = r;
    }
  }
}

// ---------------------------------------------------------------------------
extern "C" void kernel_launch(void* const* d_in, const int* in_sizes, int n_in,
                              void* d_out, int out_size, void* d_ws, size_t ws_size,
                              hipStream_t stream) {
  const float* x     = (const float*)d_in[0];
  const float* wgt   = (const float*)d_in[1];
  const float* bias  = (const float*)d_in[2];
  const float* mnw   = (const float*)d_in[3];
  const float* vnw   = (const float*)d_in[4];
  const float* pos_w = (const float*)d_in[5];
  // pos_b (d_in[6]) cancels in the softmax — unused.
  float* out = (float*)d_out;

  float* ws      = (float*)d_ws;
  float* inv_m2  = ws;                              // NB*NT*NH = 100352
  float* mean_ln = inv_m2 + (size_t)NB * NT * NH;   // 25088
  float* var_ln  = mean_ln + (size_t)NB * NT;       // 25088
  float* xp      = var_ln + (size_t)NB * NT;        // NB*NP*NC = 4816896 (16B aligned)
  // total ~19.9 MB of workspace

  hipLaunchKernelGGL(k_norm_pool, dim3(NB * NP), dim3(256), 0, stream,
                     x, inv_m2, mean_ln, var_ln, (float4*)xp);
  hipLaunchKernelGGL(k_fused, dim3(NB * PSZ), dim3(192), 0, stream,
                     (const float4*)xp, pos_w, mnw, vnw, (const float4*)x,
                     (const float4*)wgt, (const float4*)bias,
                     inv_m2, mean_ln, var_ln, (float4*)out);
}

// Round 7
// 168.535 us; speedup vs baseline: 1.3808x; 1.2678x over previous
//
#include <hip/hip_runtime.h>

#define NB   32
#define NT   784
#define NC   768
#define NH   4
#define CH   192
#define PSZ  14
#define NP   196
#define RESO 28
#define EPSV 1e-5f
#define CSL  32            // channels per slice (inside one head: 192 = 6*32)
#define NSLC (NC / CSL)    // 24 slices
#define BTH  448           // 7 waves: thread = (jx = tid>>5, ch = tid&31)

// ---------------------------------------------------------------------------
// K1: wave-per-token group-m2 norm + per-token mean/var + 2x2 pool.
// grid = NB*NP blocks of 256 (4 waves = 4 tokens of one patch). UNCHANGED (R3).
// ---------------------------------------------------------------------------
__global__ __launch_bounds__(256) void k_norm_pool(
    const float* __restrict__ x,
    float* __restrict__ inv_m2, float* __restrict__ mean_ln,
    float* __restrict__ var_ln, float4* __restrict__ xp4) {
  __shared__ float4 xl4[4 * 192];  // 12.3 KB
  int bid = blockIdx.x;
  int b = bid / NP, ip = bid % NP;
  int pr = ip / PSZ, pc = ip % PSZ;
  int tid = threadIdx.x;
  int k = tid >> 6, lane = tid & 63;
  int t = (2 * pr + (k >> 1)) * RESO + (2 * pc + (k & 1));

  const float4* row = (const float4*)(x + (size_t)(b * NT + t) * NC);
  int f4b = (lane >> 4) * 48 + (lane & 15) * 3;  // lane's base float4 index
  float4 v0 = row[f4b], v1 = row[f4b + 1], v2 = row[f4b + 2];

  // group-m2: all 12 channels of this lane belong to one head
  float d = v0.x * v0.x + v0.y * v0.y + v0.z * v0.z + v0.w * v0.w +
            v1.x * v1.x + v1.y * v1.y + v1.z * v1.z + v1.w * v1.w +
            v2.x * v2.x + v2.y * v2.y + v2.z * v2.z + v2.w * v2.w;
#pragma unroll
  for (int s = 1; s <= 8; s <<= 1) d += __shfl_xor(d, s, 64);
  float iv = rsqrtf(d * (1.f / CH) + EPSV);
  if ((lane & 15) == 0)
    inv_m2[(size_t)(b * NT + t) * NH + (lane >> 4)] = iv;

  v0.x *= iv; v0.y *= iv; v0.z *= iv; v0.w *= iv;
  v1.x *= iv; v1.y *= iv; v1.z *= iv; v1.w *= iv;
  v2.x *= iv; v2.y *= iv; v2.z *= iv; v2.w *= iv;

  float sm = v0.x + v0.y + v0.z + v0.w + v1.x + v1.y + v1.z + v1.w +
             v2.x + v2.y + v2.z + v2.w;
  float sq = v0.x * v0.x + v0.y * v0.y + v0.z * v0.z + v0.w * v0.w +
             v1.x * v1.x + v1.y * v1.y + v1.z * v1.z + v1.w * v1.w +
             v2.x * v2.x + v2.y * v2.y + v2.z * v2.z + v2.w * v2.w;
#pragma unroll
  for (int s = 1; s <= 32; s <<= 1) {
    sm += __shfl_xor(sm, s, 64);
    sq += __shfl_xor(sq, s, 64);
  }
  if (lane == 0) {
    float mean = sm / (float)NC;
    mean_ln[b * NT + t] = mean;
    var_ln[b * NT + t] = (sq - (float)NC * mean * mean) / (float)(NC - 1);
  }

  xl4[k * 192 + f4b]     = v0;
  xl4[k * 192 + f4b + 1] = v1;
  xl4[k * 192 + f4b + 2] = v2;
  __syncthreads();

  if (tid < 192) {
    float4 a = xl4[tid], bb = xl4[192 + tid], c = xl4[384 + tid], dd = xl4[576 + tid];
    float4 r;
    r.x = (a.x + bb.x + c.x + dd.x) * 0.25f;
    r.y = (a.y + bb.y + c.y + dd.y) * 0.25f;
    r.z = (a.z + bb.z + c.z + dd.z) * 0.25f;
    r.w = (a.w + bb.w + c.w + dd.w) * 0.25f;
    xp4[(size_t)(b * NP + ip) * 192 + tid] = r;
  }
}

// ---------------------------------------------------------------------------
// K2: separable conv + blend + affine + store, LDS-staged xp slice.
// grid = NB*NSLC = 768 blocks (XCD-swizzled; exactly 3/CU, balanced) of 448.
// Block = (b, 32-channel slice s) -- slice lies inside head hs = s/6.
// Stage xp[b][:, slice] (25 KB) into LDS ONCE; all 14 jx columns read it
// from LDS -> xp global traffic drops 14x (the measured L1-path bottleneck).
// Thread = (jx = tid>>5, ch = tid&31); Pass A/B structure identical to R3
// (VGPR ~60 proven), only the source of v changes (LDS, conflict-free).
// ---------------------------------------------------------------------------
__global__ __launch_bounds__(BTH) void k_fused(
    const float4* __restrict__ xp4, const float* __restrict__ pos_w,
    const float* __restrict__ mnw, const float* __restrict__ vnw,
    const float* __restrict__ x,
    const float* __restrict__ weight, const float* __restrict__ bias,
    const float* __restrict__ inv_m2, const float* __restrict__ mean_ln,
    const float* __restrict__ var_ln, float* __restrict__ out) {
  __shared__ float4 sxp4[NP * (CSL / 4)];  // 196*8 float4 = 25088 B
  __shared__ float sF[PSZ * PSZ];          // F table for head hs (jx rows)
  __shared__ float sG[PSZ * PSZ];          // G table for head hs (jy rows)
  __shared__ float tstat[NT][3];           // per token: inv_m2[hs], mean, var (9.4 KB)

  int bid0 = blockIdx.x;
  int bidS = (bid0 & 7) * 96 + (bid0 >> 3);  // bijective XCD swizzle (768 = 8*96)
  int b = bidS / NSLC, s = bidS % NSLC;
  int hs = s / 6;                            // head of this 32-channel slice
  int tid = threadIdx.x;
  int jx = tid >> 5;                         // 0..13 (half-wave uniform)
  int ch = tid & 31;
  int c = s * CSL + ch;

  // ---- per-head separable softmax tables (disjoint thread ranges)
  if (tid < PSZ) {                       // F row jf = tid: w0 on x-axis
    int jf = tid;
    float w0 = pos_w[hs * 3 + 0], w2 = pos_w[hs * 3 + 2];
    float e[PSZ], mx = -1e30f;
#pragma unroll
    for (int i = 0; i < PSZ; ++i) {
      float dd = (float)(jf - i);
      float sc = w0 * dd + w2 * dd * dd;
      e[i] = sc; mx = fmaxf(mx, sc);
    }
    float sum = 0.f;
#pragma unroll
    for (int i = 0; i < PSZ; ++i) { e[i] = expf(e[i] - mx); sum += e[i]; }
    float invs = 1.f / sum;
#pragma unroll
    for (int i = 0; i < PSZ; ++i) sF[jf * PSZ + i] = e[i] * invs;
  }
  if (tid >= 64 && tid < 64 + PSZ) {     // G row jr = tid-64: w1 on y-axis
    int jr = tid - 64;
    float w1 = pos_w[hs * 3 + 1], w2 = pos_w[hs * 3 + 2];
    float e[PSZ], mx = -1e30f;
#pragma unroll
    for (int i = 0; i < PSZ; ++i) {
      float dd = (float)(jr - i);
      float sc = w1 * dd + w2 * dd * dd;
      e[i] = sc; mx = fmaxf(mx, sc);
    }
    float sum = 0.f;
#pragma unroll
    for (int i = 0; i < PSZ; ++i) { e[i] = expf(e[i] - mx); sum += e[i]; }
    float invs = 1.f / sum;
#pragma unroll
    for (int i = 0; i < PSZ; ++i) sG[jr * PSZ + i] = e[i] * invs;
  }

  // ---- stage xp slice: 1568 float4, coalesced 128B runs per patch
  {
    const float4* src = xp4 + (size_t)b * NP * (NC / 4) + s * (CSL / 4);
    for (int i = tid; i < NP * (CSL / 4); i += BTH) {
      int p = i >> 3, q = i & 7;
      sxp4[i] = src[(size_t)p * (NC / 4) + q];
    }
  }
  // ---- stage per-token stats for head hs
  for (int i = tid; i < NT; i += BTH) {
    size_t o = (size_t)(b * NT + i);
    tstat[i][0] = inv_m2[o * NH + hs];
    tstat[i][1] = mean_ln[o];
    tstat[i][2] = var_ln[o];
  }

  // gates: uniform per block, compute per-thread (hides under staging)
  float mw = 1.f / (1.f + expf(-mnw[hs]));
  float vw = 1.f / (1.f + expf(-vnw[hs]));
  float omw = 1.f - mw, ovw = 1.f - vw;
  float wv = weight[c], bv = bias[c];

  __syncthreads();

  // ---- Pass A: x-direction 14-tap contraction from LDS (bank = ch: clean)
  float t1[PSZ], t2[PSZ];
#pragma unroll
  for (int iy = 0; iy < PSZ; ++iy) { t1[iy] = 0.f; t2[iy] = 0.f; }

  const float* sx = (const float*)sxp4;
#pragma unroll
  for (int iy = 0; iy < PSZ; ++iy) {
#pragma unroll
    for (int ix = 0; ix < PSZ; ++ix) {
      float f = sF[jx * PSZ + ix];              // half-wave uniform broadcast
      float v = sx[(iy * PSZ + ix) * CSL + ch]; // conflict-free
      t1[iy] += f * v;
      t2[iy] += f * (v * v);
    }
  }

  // ---- Pass B + epilogue
#pragma unroll 1
  for (int jy = 0; jy < PSZ; ++jy) {
    float m = 0.f, q = 0.f;
#pragma unroll
    for (int iy = 0; iy < PSZ; ++iy) {
      float g = sG[jy * PSZ + iy];  // half-wave uniform broadcast
      m += g * t1[iy];
      q += g * t2[iy];
    }
    float p = fmaxf(q - m * m, 0.f);
    float mb = omw * m, vb = ovw * p;

#pragma unroll
    for (int kk = 0; kk < 4; ++kk) {
      int t = (2 * jy + (kk >> 1)) * RESO + (2 * jx + (kk & 1));
      size_t xo = (size_t)(b * NT + t) * NC + c;
      float ivv = tstat[t][0];
      float ml  = tstat[t][1], vl = tstat[t][2];

      float xn = x[xo] * ivv;
      float mr = mb + mw * ml;
      float vr = vb + vw * vl;
      out[xo] = (xn - mr) * rsqrtf(vr + EPSV) * wv + bv;
    }
  }
}

// ---------------------------------------------------------------------------
extern "C" void kernel_launch(void* const* d_in, const int* in_sizes, int n_in,
                              void* d_out, int out_size, void* d_ws, size_t ws_size,
                              hipStream_t stream) {
  const float* x     = (const float*)d_in[0];
  const float* wgt   = (const float*)d_in[1];
  const float* bias  = (const float*)d_in[2];
  const float* mnw   = (const float*)d_in[3];
  const float* vnw   = (const float*)d_in[4];
  const float* pos_w = (const float*)d_in[5];
  // pos_b (d_in[6]) cancels in the softmax — unused.
  float* out = (float*)d_out;

  float* ws      = (float*)d_ws;
  float* inv_m2  = ws;                              // NB*NT*NH = 100352
  float* mean_ln = inv_m2 + (size_t)NB * NT * NH;   // 25088
  float* var_ln  = mean_ln + (size_t)NB * NT;       // 25088
  float* xp      = var_ln + (size_t)NB * NT;        // NB*NP*NC = 4816896 (16B aligned)
  // total ~19.9 MB of workspace

  hipLaunchKernelGGL(k_norm_pool, dim3(NB * NP), dim3(256), 0, stream,
                     x, inv_m2, mean_ln, var_ln, (float4*)xp);
  hipLaunchKernelGGL(k_fused, dim3(NB * NSLC), dim3(BTH), 0, stream,
                     (const float4*)xp, pos_w, mnw, vnw, x, wgt, bias,
                     inv_m2, mean_ln, var_ln, out);
}

// Round 8
// 165.094 us; speedup vs baseline: 1.4095x; 1.0208x over previous
//
#include <hip/hip_runtime.h>

#define NB   32
#define NT   784
#define NC   768
#define NH   4
#define CH   192
#define PSZ  14
#define NP   196
#define RESO 28
#define EPSV 1e-5f
#define CSL  32            // channels per slice (inside one head: 192 = 6*32)
#define NSLC (NC / CSL)    // 24 slices
#define BTH  448           // 7 waves: thread = (jx = tid>>5, ch = tid&31)

// ---------------------------------------------------------------------------
// K1: wave-per-token group-m2 norm + per-token mean/var + 2x2 pool.
// grid = NB*NP blocks of 256 (4 waves = 4 tokens of one patch). UNCHANGED.
// ---------------------------------------------------------------------------
__global__ __launch_bounds__(256) void k_norm_pool(
    const float* __restrict__ x,
    float* __restrict__ inv_m2, float* __restrict__ mean_ln,
    float* __restrict__ var_ln, float4* __restrict__ xp4) {
  __shared__ float4 xl4[4 * 192];  // 12.3 KB
  int bid = blockIdx.x;
  int b = bid / NP, ip = bid % NP;
  int pr = ip / PSZ, pc = ip % PSZ;
  int tid = threadIdx.x;
  int k = tid >> 6, lane = tid & 63;
  int t = (2 * pr + (k >> 1)) * RESO + (2 * pc + (k & 1));

  const float4* row = (const float4*)(x + (size_t)(b * NT + t) * NC);
  int f4b = (lane >> 4) * 48 + (lane & 15) * 3;  // lane's base float4 index
  float4 v0 = row[f4b], v1 = row[f4b + 1], v2 = row[f4b + 2];

  // group-m2: all 12 channels of this lane belong to one head
  float d = v0.x * v0.x + v0.y * v0.y + v0.z * v0.z + v0.w * v0.w +
            v1.x * v1.x + v1.y * v1.y + v1.z * v1.z + v1.w * v1.w +
            v2.x * v2.x + v2.y * v2.y + v2.z * v2.z + v2.w * v2.w;
#pragma unroll
  for (int s = 1; s <= 8; s <<= 1) d += __shfl_xor(d, s, 64);
  float iv = rsqrtf(d * (1.f / CH) + EPSV);
  if ((lane & 15) == 0)
    inv_m2[(size_t)(b * NT + t) * NH + (lane >> 4)] = iv;

  v0.x *= iv; v0.y *= iv; v0.z *= iv; v0.w *= iv;
  v1.x *= iv; v1.y *= iv; v1.z *= iv; v1.w *= iv;
  v2.x *= iv; v2.y *= iv; v2.z *= iv; v2.w *= iv;

  float sm = v0.x + v0.y + v0.z + v0.w + v1.x + v1.y + v1.z + v1.w +
             v2.x + v2.y + v2.z + v2.w;
  float sq = v0.x * v0.x + v0.y * v0.y + v0.z * v0.z + v0.w * v0.w +
             v1.x * v1.x + v1.y * v1.y + v1.z * v1.z + v1.w * v1.w +
             v2.x * v2.x + v2.y * v2.y + v2.z * v2.z + v2.w * v2.w;
#pragma unroll
  for (int s = 1; s <= 32; s <<= 1) {
    sm += __shfl_xor(sm, s, 64);
    sq += __shfl_xor(sq, s, 64);
  }
  if (lane == 0) {
    float mean = sm / (float)NC;
    mean_ln[b * NT + t] = mean;
    var_ln[b * NT + t] = (sq - (float)NC * mean * mean) / (float)(NC - 1);
  }

  xl4[k * 192 + f4b]     = v0;
  xl4[k * 192 + f4b + 1] = v1;
  xl4[k * 192 + f4b + 2] = v2;
  __syncthreads();

  if (tid < 192) {
    float4 a = xl4[tid], bb = xl4[192 + tid], c = xl4[384 + tid], dd = xl4[576 + tid];
    float4 r;
    r.x = (a.x + bb.x + c.x + dd.x) * 0.25f;
    r.y = (a.y + bb.y + c.y + dd.y) * 0.25f;
    r.z = (a.z + bb.z + c.z + dd.z) * 0.25f;
    r.w = (a.w + bb.w + c.w + dd.w) * 0.25f;
    xp4[(size_t)(b * NP + ip) * 192 + tid] = r;
  }
}

// ---------------------------------------------------------------------------
// K2: separable conv + blend + affine + store; LDS-staged xp slice and
// VECTORIZED epilogue via in-LDS mb/vb transpose.
// grid = NB*NSLC = 768 blocks of 448 (XCD-swizzled; 3/CU, 4 LDS-resident).
// Pass A/B identical to R7 (proven). New: Pass B is chunked per 2 jy; each
// chunk writes mb/vb[jy][jx][ch] into LDS (union'd into dead sxp4), then
// threads re-map to (token,f4slot) and do float4 x-load/out-store:
// 112 scalar vmem insts/thread -> 28 float4 insts (the measured issue cost).
// ---------------------------------------------------------------------------
__global__ __launch_bounds__(BTH) void k_fused(
    const float4* __restrict__ xp4, const float* __restrict__ pos_w,
    const float* __restrict__ mnw, const float* __restrict__ vnw,
    const float4* __restrict__ x4,
    const float4* __restrict__ weight4, const float4* __restrict__ bias4,
    const float* __restrict__ inv_m2, const float* __restrict__ mean_ln,
    const float* __restrict__ var_ln, float4* __restrict__ out4) {
  __shared__ float4 sxp4[NP * (CSL / 4)];  // 25088 B; REUSED as smv after Pass A
  __shared__ float sF[PSZ * PSZ];          // F table for head hs (jx rows)
  __shared__ float sG[PSZ * PSZ];          // G table for head hs (jy rows)
  __shared__ float tstat[NT][3];           // per token: inv_m2[hs], mean, var
  __shared__ float4 sWB[2][CSL / 4];       // weight4 / bias4 for this slice

  int bid0 = blockIdx.x;
  int bidS = (bid0 & 7) * 96 + (bid0 >> 3);  // bijective XCD swizzle (768 = 8*96)
  int b = bidS / NSLC, s = bidS % NSLC;
  int hs = s / 6;                            // head of this 32-channel slice
  int tid = threadIdx.x;
  int jx = tid >> 5;                         // 0..13 (half-wave uniform)
  int ch = tid & 31;

  // ---- per-head separable softmax tables (disjoint thread ranges)
  if (tid < PSZ) {                       // F row jf = tid: w0 on x-axis
    int jf = tid;
    float w0 = pos_w[hs * 3 + 0], w2 = pos_w[hs * 3 + 2];
    float e[PSZ], mx = -1e30f;
#pragma unroll
    for (int i = 0; i < PSZ; ++i) {
      float dd = (float)(jf - i);
      float sc = w0 * dd + w2 * dd * dd;
      e[i] = sc; mx = fmaxf(mx, sc);
    }
    float sum = 0.f;
#pragma unroll
    for (int i = 0; i < PSZ; ++i) { e[i] = expf(e[i] - mx); sum += e[i]; }
    float invs = 1.f / sum;
#pragma unroll
    for (int i = 0; i < PSZ; ++i) sF[jf * PSZ + i] = e[i] * invs;
  }
  if (tid >= 64 && tid < 64 + PSZ) {     // G row jr = tid-64: w1 on y-axis
    int jr = tid - 64;
    float w1 = pos_w[hs * 3 + 1], w2 = pos_w[hs * 3 + 2];
    float e[PSZ], mx = -1e30f;
#pragma unroll
    for (int i = 0; i < PSZ; ++i) {
      float dd = (float)(jr - i);
      float sc = w1 * dd + w2 * dd * dd;
      e[i] = sc; mx = fmaxf(mx, sc);
    }
    float sum = 0.f;
#pragma unroll
    for (int i = 0; i < PSZ; ++i) { e[i] = expf(e[i] - mx); sum += e[i]; }
    float invs = 1.f / sum;
#pragma unroll
    for (int i = 0; i < PSZ; ++i) sG[jr * PSZ + i] = e[i] * invs;
  }
  if (tid >= 128 && tid < 128 + CSL / 4) {          // weight slice
    sWB[0][tid - 128] = weight4[s * (CSL / 4) + (tid - 128)];
  }
  if (tid >= 160 && tid < 160 + CSL / 4) {          // bias slice
    sWB[1][tid - 160] = bias4[s * (CSL / 4) + (tid - 160)];
  }

  // ---- stage xp slice: 1568 float4, coalesced 128B runs per patch
  {
    const float4* src = xp4 + (size_t)b * NP * (NC / 4) + s * (CSL / 4);
    for (int i = tid; i < NP * (CSL / 4); i += BTH) {
      int p = i >> 3, q = i & 7;
      sxp4[i] = src[(size_t)p * (NC / 4) + q];
    }
  }
  // ---- stage per-token stats for head hs
  for (int i = tid; i < NT; i += BTH) {
    size_t o = (size_t)(b * NT + i);
    tstat[i][0] = inv_m2[o * NH + hs];
    tstat[i][1] = mean_ln[o];
    tstat[i][2] = var_ln[o];
  }

  // gates: uniform per block, compute per-thread (hides under staging)
  float mw = 1.f / (1.f + expf(-mnw[hs]));
  float vw = 1.f / (1.f + expf(-vnw[hs]));
  float omw = 1.f - mw, ovw = 1.f - vw;

  __syncthreads();

  // ---- Pass A: x-direction 14-tap contraction from LDS (bank = ch: clean)
  float t1[PSZ], t2[PSZ];
#pragma unroll
  for (int iy = 0; iy < PSZ; ++iy) { t1[iy] = 0.f; t2[iy] = 0.f; }

  const float* sx = (const float*)sxp4;
#pragma unroll
  for (int iy = 0; iy < PSZ; ++iy) {
#pragma unroll
    for (int ix = 0; ix < PSZ; ++ix) {
      float f = sF[jx * PSZ + ix];              // half-wave uniform broadcast
      float v = sx[(iy * PSZ + ix) * CSL + ch]; // conflict-free
      t1[iy] += f * v;
      t2[iy] += f * (v * v);
    }
  }
  __syncthreads();   // all Pass-A reads done -> sxp4 space reusable as smv

  // ---- Pass B + vectorized epilogue, chunked per 2 jy.
  // smv layout (floats, inside sxp4): [m/v 0..1 via +2][jyl 0..1][jx 0..13][ch 0..31]
  float* smv = (float*)sxp4;   // uses 2*2*14*32*4 = 7168 B of 25088
  const float4* xb = x4 + (size_t)b * NT * (NC / 4) + s * (CSL / 4);
  float4* ob = out4 + (size_t)b * NT * (NC / 4) + s * (CSL / 4);

#pragma unroll 1
  for (int chunk = 0; chunk < 7; ++chunk) {
    // Pass B for jy = 2*chunk + {0,1}
#pragma unroll
    for (int jyl = 0; jyl < 2; ++jyl) {
      int jy = chunk * 2 + jyl;
      float m = 0.f, q = 0.f;
#pragma unroll
      for (int iy = 0; iy < PSZ; ++iy) {
        float g = sG[jy * PSZ + iy];  // half-wave uniform broadcast
        m += g * t1[iy];
        q += g * t2[iy];
      }
      float p = fmaxf(q - m * m, 0.f);
      smv[(jyl * PSZ + jx) * CSL + ch]            = omw * m;  // mb
      smv[((2 + jyl) * PSZ + jx) * CSL + ch]      = ovw * p;  // vb
    }
    __syncthreads();

    // epilogue for token rows 4*chunk .. 4*chunk+3 (896 f4-items, 2/thread)
#pragma unroll
    for (int k = 0; k < 2; ++k) {
      int w = tid + BTH * k;          // 0..895
      int slot = w & 7;               // f4 slot within slice
      int r2 = w >> 3;                // 0..111
      int tcol = r2 % 28, trl = r2 / 28;
      int trow = chunk * 4 + trl;
      int t = trow * RESO + tcol;
      int jyl = trl >> 1, jx2 = tcol >> 1;

      float4 mb4 = *(const float4*)&smv[(jyl * PSZ + jx2) * CSL + slot * 4];
      float4 vb4 = *(const float4*)&smv[((2 + jyl) * PSZ + jx2) * CSL + slot * 4];
      float ivv = tstat[t][0];
      float mr = mw * tstat[t][1];
      float vr = vw * tstat[t][2] + EPSV;
      float4 wv = sWB[0][slot], bv = sWB[1][slot];

      float4 xv = xb[(size_t)t * (NC / 4) + slot];
      float4 r;
      r.x = (xv.x * ivv - (mb4.x + mr)) * rsqrtf(vb4.x + vr) * wv.x + bv.x;
      r.y = (xv.y * ivv - (mb4.y + mr)) * rsqrtf(vb4.y + vr) * wv.y + bv.y;
      r.z = (xv.z * ivv - (mb4.z + mr)) * rsqrtf(vb4.z + vr) * wv.z + bv.z;
      r.w = (xv.w * ivv - (mb4.w + mr)) * rsqrtf(vb4.w + vr) * wv.w + bv.w;
      ob[(size_t)t * (NC / 4) + slot] = r;
    }
    __syncthreads();   // before next chunk overwrites smv
  }
}

// ---------------------------------------------------------------------------
extern "C" void kernel_launch(void* const* d_in, const int* in_sizes, int n_in,
                              void* d_out, int out_size, void* d_ws, size_t ws_size,
                              hipStream_t stream) {
  const float* x     = (const float*)d_in[0];
  const float* wgt   = (const float*)d_in[1];
  const float* bias  = (const float*)d_in[2];
  const float* mnw   = (const float*)d_in[3];
  const float* vnw   = (const float*)d_in[4];
  const float* pos_w = (const float*)d_in[5];
  // pos_b (d_in[6]) cancels in the softmax — unused.
  float* out = (float*)d_out;

  float* ws      = (float*)d_ws;
  float* inv_m2  = ws;                              // NB*NT*NH = 100352
  float* mean_ln = inv_m2 + (size_t)NB * NT * NH;   // 25088
  float* var_ln  = mean_ln + (size_t)NB * NT;       // 25088
  float* xp      = var_ln + (size_t)NB * NT;        // NB*NP*NC = 4816896 (16B aligned)
  // total ~19.9 MB of workspace

  hipLaunchKernelGGL(k_norm_pool, dim3(NB * NP), dim3(256), 0, stream,
                     x, inv_m2, mean_ln, var_ln, (float4*)xp);
  hipLaunchKernelGGL(k_fused, dim3(NB * NSLC), dim3(BTH), 0, stream,
                     (const float4*)xp, pos_w, mnw, vnw, (const float4*)x,
                     (const float4*)wgt, (const float4*)bias,
                     inv_m2, mean_ln, var_ln, (float4*)out);
}